// Round 4
// baseline (143.744 us; speedup 1.0000x reference)
//
#include <hip/hip_runtime.h>

// Reference: out[b,h,w,i] = in[b, h + i/8, w + i%8, 0]
//   in : (8, 512, 512, 1) f32   (8.4 MB, L2/L3-resident)
//   out: (8, 505, 505, 64) f32  (522 MB -> write-BW bound)
//
// R2 structure (best so far, 97.4 us): grid-stride, each thread writes one
// float4 of output from 4 scalar input loads (L1/L2-hits).
// R4 probe: plain store instead of nontemporal (fill kernel hits 6.9 TB/s
// through L2 with default stores; nt bypass may burst less efficiently).

#define BATCH   8
#define W_IN    512
#define HW_OUT  505

typedef float f32x4 __attribute__((ext_vector_type(4)));

__global__ __launch_bounds__(256) void unfold_kernel(
    const float* __restrict__ in, float* __restrict__ out, int total4)
{
    int idx    = blockIdx.x * blockDim.x + threadIdx.x;
    int stride = gridDim.x * blockDim.x;
    f32x4* __restrict__ out4 = reinterpret_cast<f32x4*>(out);

    for (int t = idx; t < total4; t += stride) {
        int i4  = t & 15;        // 16 float4 per output pixel (64 floats)
        int pos = t >> 4;        // flat (b, h, w)
        int w   = pos % HW_OUT;
        int tmp = pos / HW_OUT;
        int h   = tmp % HW_OUT;
        int b   = tmp / HW_OUT;

        int r = i4 >> 1;         // (4*i4)/8  : window row 0..7
        int c = (i4 & 1) * 4;    // (4*i4)%8  : window col base {0,4}

        const float* __restrict__ src =
            in + ((b * W_IN + h + r) * W_IN + (w + c));

        f32x4 v;
        v.x = src[0];
        v.y = src[1];
        v.z = src[2];
        v.w = src[3];
        out4[t] = v;             // plain store (was: nontemporal)
    }
}

extern "C" void kernel_launch(void* const* d_in, const int* in_sizes, int n_in,
                              void* d_out, int out_size, void* d_ws, size_t ws_size,
                              hipStream_t stream)
{
    const float* in  = (const float*)d_in[0];   // (8,512,512,1) f32
    float*       out = (float*)d_out;           // (8,505,505,64) f32

    const int total4 = BATCH * HW_OUT * HW_OUT * 16;  // 32,643,200 float4
    const int block  = 256;
    int grid = (total4 + block - 1) / block;
    const int max_grid = 256 * 8;                     // 2048 blocks, grid-stride
    if (grid > max_grid) grid = max_grid;

    unfold_kernel<<<grid, block, 0, stream>>>(in, out, total4);
}

// Round 5
// 107.627 us; speedup vs baseline: 1.3356x; 1.3356x over previous
//
#include <hip/hip_runtime.h>

// Reference: out[b,h,w,i] = in[b, h + i/8, w + i%8, 0]
//   in : (8, 512, 512, 1) f32   (8.4 MB)
//   out: (8, 505, 505, 64) f32  (522 MB -> write-BW bound)
//
// Ladder: R2 grid-stride + 4-scalar-load + NT store = 97.4 us (5.36 TB/s eff)
//         R3 row-block + unaligned-16B-load + NT    = 108.8 us (bad load split)
//         R4 grid-stride + 4-scalar-load + plain    = 143.7 us (L2 thrash)
// R5: row-block + 4-scalar-load + NT. Per-block read set = 8 input rows
// (16 KB, L1-resident); stores contiguous per block; NT keeps L2 clean.

#define BATCH   8
#define W_IN    512
#define HW_OUT  505
#define ROW4    (HW_OUT * 16)   // 8080 float4 per (b,h) output row

typedef float f32x4 __attribute__((ext_vector_type(4)));

__global__ __launch_bounds__(256) void unfold_row_kernel(
    const float* __restrict__ in, float* __restrict__ out)
{
    int bh = blockIdx.x;               // 0..(8*505-1)
    int b  = bh / HW_OUT;
    int h  = bh - b * HW_OUT;

    const float* __restrict__ row_base = in + (b * W_IN + h) * W_IN;
    f32x4* __restrict__ out4 = reinterpret_cast<f32x4*>(out) + (size_t)bh * ROW4;

    for (int t = threadIdx.x; t < ROW4; t += 256) {
        int i4 = t & 15;               // which float4 within the 64-ch pixel
        int w  = t >> 4;               // output column
        int r  = i4 >> 1;              // window row 0..7
        int c  = (i4 & 1) << 2;        // window col base {0,4}

        const float* __restrict__ src = row_base + (r << 9) + w + c;

        f32x4 v;
        v.x = src[0];
        v.y = src[1];
        v.z = src[2];
        v.w = src[3];
        __builtin_nontemporal_store(v, out4 + t);
    }
}

extern "C" void kernel_launch(void* const* d_in, const int* in_sizes, int n_in,
                              void* d_out, int out_size, void* d_ws, size_t ws_size,
                              hipStream_t stream)
{
    const float* in  = (const float*)d_in[0];   // (8,512,512,1) f32
    float*       out = (float*)d_out;           // (8,505,505,64) f32

    const int grid = BATCH * HW_OUT;            // 4040 blocks, one per output row
    unfold_row_kernel<<<grid, 256, 0, stream>>>(in, out);
}

// Round 6
// 104.245 us; speedup vs baseline: 1.3789x; 1.0324x over previous
//
#include <hip/hip_runtime.h>

// Reference: out[b,h,w,i] = in[b, h + i/8, w + i%8, 0]
//   in : (8, 512, 512, 1) f32   (8.4 MB)
//   out: (8, 505, 505, 64) f32  (522 MB -> write-BW bound)
//
// Ladder: R2 grid-stride + 4-scalar-load + NT store = 97.4 us (5.36 TB/s)
//         R3 row-block + unaligned-16B-load + NT    = 108.8 us
//         R4 grid-stride + 4-scalar-load + plain    = 143.7 us (L1/L2 thrash)
//         R5 row-block + 4-scalar-load + NT         = 107.6 us (write scatter)
// R6 probe: row-block + LDS-staged reads + PLAIN stores. The fill kernel
// sustains 6.9 TB/s with plain stores; R4 showed plain stores die from read
// interference. LDS staging makes the store phase read-free: if the L2-routed
// store path then hits fill rate, we beat NT's ~5.4 TB/s ceiling.
//
// LDS row stride 516 floats: read addr = r*516 + w + c (mod 32 banks) ->
// bank = (4r + c + w) % 32 -> exactly 2 lanes/bank (free, m136).

#define BATCH   8
#define W_IN    512
#define HW_OUT  505
#define ROW4    (HW_OUT * 16)   // 8080 float4 per (b,h) output row
#define LDS_STRIDE 516          // floats per staged row (pad 512 -> 516)

typedef float f32x4 __attribute__((ext_vector_type(4)));

__global__ __launch_bounds__(256) void unfold_lds_kernel(
    const float* __restrict__ in, float* __restrict__ out)
{
    __shared__ float smem[8 * LDS_STRIDE];   // 16.5 KB

    int bh = blockIdx.x;               // 0..(8*505-1)
    int b  = bh / HW_OUT;
    int h  = bh - b * HW_OUT;

    const float* __restrict__ row_base = in + (b * W_IN + h) * W_IN;
    f32x4* __restrict__ out4 = reinterpret_cast<f32x4*>(out) + (size_t)bh * ROW4;

    // Stage rows h..h+7 (8 x 512 floats) into LDS. Coalesced 16B loads,
    // address-sequential b128 LDS writes (conflict-free).
    for (int t = threadIdx.x; t < 8 * 128; t += 256) {
        int r = t >> 7;                // staged row 0..7
        int q = t & 127;               // float4 index within row
        f32x4 v = *reinterpret_cast<const f32x4*>(row_base + (r << 9) + (q << 2));
        *reinterpret_cast<f32x4*>(&smem[r * LDS_STRIDE + (q << 2)]) = v;
    }
    __syncthreads();

    // Store phase: zero global reads -> plain stores get the full L2 path.
    for (int t = threadIdx.x; t < ROW4; t += 256) {
        int i4 = t & 15;               // which float4 within the 64-ch pixel
        int w  = t >> 4;               // output column
        int r  = i4 >> 1;              // window row 0..7
        int c  = (i4 & 1) << 2;        // window col base {0,4}

        const float* __restrict__ s = &smem[r * LDS_STRIDE + w + c];
        f32x4 v;
        v.x = s[0];
        v.y = s[1];
        v.z = s[2];
        v.w = s[3];
        out4[t] = v;                   // PLAIN store (L2-routed)
    }
}

extern "C" void kernel_launch(void* const* d_in, const int* in_sizes, int n_in,
                              void* d_out, int out_size, void* d_ws, size_t ws_size,
                              hipStream_t stream)
{
    const float* in  = (const float*)d_in[0];   // (8,512,512,1) f32
    float*       out = (float*)d_out;           // (8,505,505,64) f32

    const int grid = BATCH * HW_OUT;            // 4040 blocks, one per output row
    unfold_lds_kernel<<<grid, 256, 0, stream>>>(in, out);
}